// Round 7
// baseline (45.891 us; speedup 1.0000x reference)
//
#include <hip/hip_runtime.h>

// GSA loss: pred [B=2,1,64,64] fp32, token [B,4096,4096] fp32 -> scalar fp32.
// loss = 2 - s_fa/s_f - s_bb/s_b with
//   T   = sum t_ij ; s_f = sum p_i t_ij ; s_c = sum t_ij p_j (token NOT symm)
//   s_fa= sum p_i t_ij p_j ; s_b = T - s_f ; s_bb = T - s_f - s_c + s_fa
//
// R2: killed same-address fp64 atomics (117.9 -> 29.6 us).
// R3/R4/R5: MLP/pipelining variants all NEUTRAL (29.6-30.1) -> stage 1 is at
//   the read-stream ceiling (~5.4 TB/s effective; m13's 6.29 is a copy mix).
// R6: remove the remaining FIXED overhead: fuse stage 2 via last-block-done.
//   - partials stored with agent-scope stores (cross-XCD visibility, G16;
//     plain loads on the reader could hit stale replay-(N-1) lines in its L2)
//   - two-level counter tree: 8 padded leaf counters (64 blocks each) + root.
//     R0 lesson: same-address RMW ~11ns each; 512 on one line = +5us tail,
//     64/line in parallel = <1us.
//   - last block reduces 512 partials with agent-scope fp64 loads, writes out.

#define HW    4096
#define HW4   1024   // HW / 4
#define NBLK  512
#define RPW   4      // rows per wave; 512 blk * 4 waves * 4 rows = 8192 = B*HW
#define NGRP  8      // leaf counter groups (64 blocks each)

struct alignas(32) D4 { double t, f, c, fa; };

// d_ws layout:
//   [0, 16384)        D4 part[512]
//   [16384, 16384+64*NGRP)  leaf counters, 1 per 64B line
//   [+64*NGRP, +64*NGRP+64) root counter
#define CTR_OFF   16384
#define CTR_BYTES (64 * (NGRP + 1))

__global__ __launch_bounds__(256, 2) void gsa_fused(
    const float* __restrict__ pred,
    const float* __restrict__ token,
    double* __restrict__ partd,      // part as doubles: part[bid*4 + {0..3}]
    unsigned* __restrict__ ctr,      // leaf g at ctr[g*16], root at ctr[NGRP*16]
    float* __restrict__ out)
{
    __shared__ float4 pj_lds[HW4];   // 16 KB: pred row for this batch
    __shared__ double sm[4][4];
    __shared__ int    last_flag;

    const float4* __restrict__ tok4  = (const float4*)token;
    const float4* __restrict__ pred4 = (const float4*)pred;

    const int bid  = blockIdx.x;         // 0..511
    const int wave = threadIdx.x >> 6;
    const int lane = threadIdx.x & 63;
    const int gw   = bid * 4 + wave;     // global wave 0..2047
    const int row0 = gw * RPW;           // 4 consecutive rows, batch-aligned
    const int b    = row0 >> 12;

    // stage pred[b,:] into LDS
    for (int k = threadIdx.x; k < HW4; k += 256)
        pj_lds[k] = pred4[b * HW4 + k];

    float pi_r[RPW];
#pragma unroll
    for (int r = 0; r < RPW; ++r)
        pi_r[r] = pred[row0 + r];

    // prologue: fill buffer A with row 0
    float4 A[16], Bv[16];
    {
        const float4* __restrict__ rp = tok4 + (size_t)row0 * HW4;
#pragma unroll
        for (int u = 0; u < 16; ++u)
            A[u] = rp[u * 64 + lane];
    }

    __syncthreads();

    float tT = 0.f, tF = 0.f, tC = 0.f, tFA = 0.f;

#pragma unroll
    for (int r = 0; r < RPW; ++r) {      // fully unrolled -> static buf index
        float4* cur = (r & 1) ? Bv : A;
        float4* nxt = (r & 1) ? A  : Bv;

        if (r + 1 < RPW) {
            const float4* __restrict__ rp = tok4 + (size_t)(row0 + r + 1) * HW4;
#pragma unroll
            for (int u = 0; u < 16; ++u)
                nxt[u] = rp[u * 64 + lane];
        }
        __builtin_amdgcn_sched_barrier(0);

        float s0 = 0.f, s1 = 0.f, d0 = 0.f, d1 = 0.f;
#pragma unroll
        for (int u = 0; u < 16; u += 2) {
            float4 pa = pj_lds[u * 64 + lane];
            float4 pb = pj_lds[(u + 1) * 64 + lane];
            s0 += cur[u].x + cur[u].y + cur[u].z + cur[u].w;
            d0 += cur[u].x * pa.x + cur[u].y * pa.y + cur[u].z * pa.z + cur[u].w * pa.w;
            s1 += cur[u+1].x + cur[u+1].y + cur[u+1].z + cur[u+1].w;
            d1 += cur[u+1].x * pb.x + cur[u+1].y * pb.y + cur[u+1].z * pb.z + cur[u+1].w * pb.w;
        }
        float s = s0 + s1, d = d0 + d1;
        float pi = pi_r[r];
        tT  += s;
        tF  += pi * s;
        tC  += d;
        tFA += pi * d;
    }

    for (int off = 32; off > 0; off >>= 1) {
        tT  += __shfl_down(tT,  off);
        tF  += __shfl_down(tF,  off);
        tC  += __shfl_down(tC,  off);
        tFA += __shfl_down(tFA, off);
    }

    if (lane == 0) {
        sm[wave][0] = (double)tT;
        sm[wave][1] = (double)tF;
        sm[wave][2] = (double)tC;
        sm[wave][3] = (double)tFA;
    }
    __syncthreads();

    // ---- publish partial + last-block-done protocol ----
    if (threadIdx.x == 0) {
        double pt  = sm[0][0] + sm[1][0] + sm[2][0] + sm[3][0];
        double pf  = sm[0][1] + sm[1][1] + sm[2][1] + sm[3][1];
        double pc  = sm[0][2] + sm[1][2] + sm[2][2] + sm[3][2];
        double pfa = sm[0][3] + sm[1][3] + sm[2][3] + sm[3][3];
        // agent-scope stores: visible past this XCD's L2
        __hip_atomic_store(&partd[bid*4+0], pt,  __ATOMIC_RELAXED, __HIP_MEMORY_SCOPE_AGENT);
        __hip_atomic_store(&partd[bid*4+1], pf,  __ATOMIC_RELAXED, __HIP_MEMORY_SCOPE_AGENT);
        __hip_atomic_store(&partd[bid*4+2], pc,  __ATOMIC_RELAXED, __HIP_MEMORY_SCOPE_AGENT);
        __hip_atomic_store(&partd[bid*4+3], pfa, __ATOMIC_RELAXED, __HIP_MEMORY_SCOPE_AGENT);
        __threadfence();                       // release

        int lst = 0;
        unsigned t = atomicAdd(&ctr[(bid >> 6) * 16], 1u);   // 64 blocks/leaf
        if (t == 63u) {                        // this block closes its group
            unsigned rt = atomicAdd(&ctr[NGRP * 16], 1u);
            lst = (rt == NGRP - 1u);           // closes the root -> last block
        }
        last_flag = lst;
    }
    __syncthreads();

    if (!last_flag) return;

    // ---- final reduction by the last block (all 256 threads) ----
    __threadfence();                           // acquire
    double aT = 0.0, aF = 0.0, aC = 0.0, aFA = 0.0;
    for (int k = threadIdx.x; k < NBLK; k += 256) {
        aT  += __hip_atomic_load(&partd[k*4+0], __ATOMIC_RELAXED, __HIP_MEMORY_SCOPE_AGENT);
        aF  += __hip_atomic_load(&partd[k*4+1], __ATOMIC_RELAXED, __HIP_MEMORY_SCOPE_AGENT);
        aC  += __hip_atomic_load(&partd[k*4+2], __ATOMIC_RELAXED, __HIP_MEMORY_SCOPE_AGENT);
        aFA += __hip_atomic_load(&partd[k*4+3], __ATOMIC_RELAXED, __HIP_MEMORY_SCOPE_AGENT);
    }

    for (int off = 32; off > 0; off >>= 1) {
        aT  += __shfl_down(aT,  off);
        aF  += __shfl_down(aF,  off);
        aC  += __shfl_down(aC,  off);
        aFA += __shfl_down(aFA, off);
    }

    __syncthreads();                           // sm[] reuse
    if (lane == 0) {
        sm[wave][0] = aT; sm[wave][1] = aF;
        sm[wave][2] = aC; sm[wave][3] = aFA;
    }
    __syncthreads();

    if (threadIdx.x == 0) {
        double T   = sm[0][0] + sm[1][0] + sm[2][0] + sm[3][0];
        double sf  = sm[0][1] + sm[1][1] + sm[2][1] + sm[3][1];
        double sc  = sm[0][2] + sm[1][2] + sm[2][2] + sm[3][2];
        double sfa = sm[0][3] + sm[1][3] + sm[2][3] + sm[3][3];
        double sb  = T - sf;
        double sbb = T - sf - sc + sfa;
        out[0] = (float)(2.0 - sfa / sf - sbb / sb);
    }
}

extern "C" void kernel_launch(void* const* d_in, const int* in_sizes, int n_in,
                              void* d_out, int out_size, void* d_ws, size_t ws_size,
                              hipStream_t stream)
{
    const float* pred  = (const float*)d_in[0];
    const float* token = (const float*)d_in[1];
    float*    out   = (float*)d_out;
    double*   partd = (double*)d_ws;
    unsigned* ctr   = (unsigned*)((char*)d_ws + CTR_OFF);

    // counters must be zero every call (poisoned once, never re-poisoned;
    // async memset is graph-capture-legal). part[] is fully overwritten.
    hipMemsetAsync((char*)d_ws + CTR_OFF, 0, CTR_BYTES, stream);

    gsa_fused<<<NBLK, 256, 0, stream>>>(pred, token, partd, ctr, out);
}

// Round 8
// 29.799 us; speedup vs baseline: 1.5400x; 1.5400x over previous
//
#include <hip/hip_runtime.h>

// GSA loss: pred [B=2,1,64,64] fp32, token [B,4096,4096] fp32 -> scalar fp32.
// loss = 2 - s_fa/s_f - s_bb/s_b with
//   T   = sum t_ij ; s_f = sum p_i t_ij ; s_c = sum t_ij p_j (token NOT symm)
//   s_fa= sum p_i t_ij p_j ; s_b = T - s_f ; s_bb = T - s_f - s_c + s_fa
//
// History:
//   R2: killed same-address fp64 atomics (117.9 -> 29.6 us). BEST.
//   R3/R4/R5: MLP/pipelining variants NEUTRAL (29.6-30.1) — duration invariant
//     to HBM-vs-L3 service => ~5.3 TB/s is the read-stream ceiling here.
//   R6: single-kernel fusion via threadfence/agent-scope REGRESSED to 45.9 us
//     (device-scope fences cost >> the ~3 us launch overhead saved). Reverted.
//   R7: R2 structure, launch_bounds(256,8) so all 2048 blocks co-reside
//     (VGPR 32 <= 64 cap, LDS 16.9KB*8 = 135KB <= 160KB) — removes the second
//     block-dispatch round (R2 measured 46% avg occupancy).

#define HW   4096
#define HW4  1024   // HW / 4
#define NBLK 2048

struct alignas(32) D4 { double t, f, c, fa; };

__global__ __launch_bounds__(256, 8) void gsa_partial(
    const float* __restrict__ pred,
    const float* __restrict__ token,
    D4* __restrict__ part)           // part[NBLK]
{
    __shared__ float4 pj_lds[HW4];   // 16 KB: pred row for this batch
    __shared__ double sm[4][4];

    const float4* __restrict__ tok4  = (const float4*)token;
    const float4* __restrict__ pred4 = (const float4*)pred;

    const int bid = blockIdx.x;      // 0..2047
    const int b   = bid >> 10;       // rows 4*bid..4*bid+3 all in batch b

    for (int k = threadIdx.x; k < HW4; k += 256)
        pj_lds[k] = pred4[b * HW4 + k];
    __syncthreads();

    const int wave = threadIdx.x >> 6;
    const int lane = threadIdx.x & 63;
    const int row  = bid * 4 + wave;            // global row in [0, B*HW)

    const float pi = pred[row];                 // wave-uniform load
    const float4* __restrict__ rowp = tok4 + (size_t)row * HW4;

    float4 t[16];
#pragma unroll
    for (int u = 0; u < 16; ++u)
        t[u] = rowp[u * 64 + lane];

    float s0 = 0.f, s1 = 0.f, d0 = 0.f, d1 = 0.f;
#pragma unroll
    for (int u = 0; u < 16; u += 2) {
        float4 pa = pj_lds[u * 64 + lane];
        float4 pb = pj_lds[(u + 1) * 64 + lane];
        s0 += t[u].x + t[u].y + t[u].z + t[u].w;
        d0 += t[u].x * pa.x + t[u].y * pa.y + t[u].z * pa.z + t[u].w * pa.w;
        s1 += t[u+1].x + t[u+1].y + t[u+1].z + t[u+1].w;
        d1 += t[u+1].x * pb.x + t[u+1].y * pb.y + t[u+1].z * pb.z + t[u+1].w * pb.w;
    }
    float s = s0 + s1, d = d0 + d1;

    float tT  = s;
    float tF  = pi * s;
    float tC  = d;
    float tFA = pi * d;

    for (int off = 32; off > 0; off >>= 1) {
        tT  += __shfl_down(tT,  off);
        tF  += __shfl_down(tF,  off);
        tC  += __shfl_down(tC,  off);
        tFA += __shfl_down(tFA, off);
    }

    if (lane == 0) {
        sm[wave][0] = (double)tT;
        sm[wave][1] = (double)tF;
        sm[wave][2] = (double)tC;
        sm[wave][3] = (double)tFA;
    }
    __syncthreads();

    if (threadIdx.x == 0) {
        D4 p;
        p.t  = sm[0][0] + sm[1][0] + sm[2][0] + sm[3][0];
        p.f  = sm[0][1] + sm[1][1] + sm[2][1] + sm[3][1];
        p.c  = sm[0][2] + sm[1][2] + sm[2][2] + sm[3][2];
        p.fa = sm[0][3] + sm[1][3] + sm[2][3] + sm[3][3];
        part[bid] = p;               // plain store — no atomics
    }
}

__global__ __launch_bounds__(256) void gsa_final(
    const D4* __restrict__ part, float* __restrict__ out)
{
    const double2* __restrict__ p2 = (const double2*)part;  // [NBLK*2]

    double aT = 0.0, aF = 0.0, aC = 0.0, aFA = 0.0;
    for (int k = threadIdx.x; k < NBLK; k += 256) {
        double2 lo = p2[k * 2 + 0];   // {t, f}
        double2 hi = p2[k * 2 + 1];   // {c, fa}
        aT += lo.x; aF += lo.y; aC += hi.x; aFA += hi.y;
    }

    for (int off = 32; off > 0; off >>= 1) {
        aT  += __shfl_down(aT,  off);
        aF  += __shfl_down(aF,  off);
        aC  += __shfl_down(aC,  off);
        aFA += __shfl_down(aFA, off);
    }

    __shared__ double sm[4][4];
    const int wave = threadIdx.x >> 6;
    const int lane = threadIdx.x & 63;
    if (lane == 0) {
        sm[wave][0] = aT; sm[wave][1] = aF;
        sm[wave][2] = aC; sm[wave][3] = aFA;
    }
    __syncthreads();

    if (threadIdx.x == 0) {
        double T   = sm[0][0] + sm[1][0] + sm[2][0] + sm[3][0];
        double sf  = sm[0][1] + sm[1][1] + sm[2][1] + sm[3][1];
        double sc  = sm[0][2] + sm[1][2] + sm[2][2] + sm[3][2];
        double sfa = sm[0][3] + sm[1][3] + sm[2][3] + sm[3][3];
        double sb  = T - sf;
        double sbb = T - sf - sc + sfa;
        out[0] = (float)(2.0 - sfa / sf - sbb / sb);
    }
}

extern "C" void kernel_launch(void* const* d_in, const int* in_sizes, int n_in,
                              void* d_out, int out_size, void* d_ws, size_t ws_size,
                              hipStream_t stream)
{
    const float* pred  = (const float*)d_in[0];
    const float* token = (const float*)d_in[1];
    float* out  = (float*)d_out;
    D4*    part = (D4*)d_ws;         // 2048 * 32 B = 64 KB scratch

    // stage 1: one token row per wave, per-block partials (every part[] slot
    // overwritten every call — no memset needed)
    gsa_partial<<<NBLK, 256, 0, stream>>>(pred, token, part);
    // stage 2: deterministic fixed-order reduction + scalar epilogue
    gsa_final<<<1, 256, 0, stream>>>(part, out);
}